// Round 8
// baseline (612.470 us; speedup 1.0000x reference)
//
#include <hip/hip_runtime.h>

#define Bb 256
#define Tt 1024
#define NT 96
#define PF 4   // h prefetch depth (per stream); no barriers => loads free-run

// CRF forward (log partition) — ONE WAVE per batch element (64 threads/block).
// Lane l owns: full row l of E=exp(trans) (EA[96]) and half of row 64+(l>>1)
// (EB[48], column-half l&1). Per step:
//   vA[l]      = sum_j EA[j]*p[j]                (96 FMA)
//   vB[64+l/2] = pair-combined half dots          (48 FMA + 1 shfl_xor(1))
//   w = v * exp(h_t) * u,  u = e^{-c}/p_prev[0]  (tag-0 probe, u=1 at t=0)
//   p' = (t<L) ? w : p;  M -= (t<L)?log(u):0
// p is broadcast through LDS, but producer == consumer == the same wave, so
// there is NO s_barrier anywhere in the loop (per-wave DS ops are in-order).
// R7 bug fixed: start_tag=94 lives in the 64..95 half => init via l==30,
// (r7 zeroed it -> p==0 -> rcp(0)=inf -> NaN).
// E pinned via scalar asm ties (r6-validated); waves_per_eu(1,1) => 512 VGPRs.
__global__ __attribute__((amdgpu_flat_work_group_size(64, 64),
                          amdgpu_waves_per_eu(1, 1)))
void crf_fwd_kernel(
    const float* __restrict__ h,       // [B][T][NT]
    const int*   __restrict__ lengths, // [B]
    const float* __restrict__ trans,   // [NT][NT] trans[to, from]
    float* __restrict__ out)           // [B]
{
    const int b   = blockIdx.x;
    const int l   = threadIdx.x;        // 0..63
    const int par = l & 1;
    const int r2  = 64 + (l >> 1);      // second row, 64..95 (same for lane pair)
    const int L   = lengths[b];

    __shared__ float p_lds[2][128];

    // EA = exp(trans[l][0..95]); EB = exp(trans[r2][par*48 .. par*48+47])
    float EA[96], EB[48];
    {
        const float4* ra = reinterpret_cast<const float4*>(trans + l * NT);
        #pragma unroll
        for (int m = 0; m < 24; ++m) {
            const float4 t4 = ra[m];
            EA[4*m+0] = __expf(t4.x); EA[4*m+1] = __expf(t4.y);
            EA[4*m+2] = __expf(t4.z); EA[4*m+3] = __expf(t4.w);
        }
        const float4* rb = reinterpret_cast<const float4*>(trans + r2 * NT + par * 48);
        #pragma unroll
        for (int m = 0; m < 12; ++m) {
            const float4 t4 = rb[m];
            EB[4*m+0] = __expf(t4.x); EB[4*m+1] = __expf(t4.y);
            EB[4*m+2] = __expf(t4.z); EB[4*m+3] = __expf(t4.w);
        }
    }
    // Pin E (asm-defined scalars can't be rematerialized/sunk) — r6-validated.
#define PIN12(A,B,C,D,E_,F,G,H,I,J,K,Lq) \
    asm volatile("" : "+v"(A), "+v"(B), "+v"(C), "+v"(D), "+v"(E_), "+v"(F), \
                      "+v"(G), "+v"(H), "+v"(I), "+v"(J), "+v"(K), "+v"(Lq));
    PIN12(EA[0],EA[1],EA[2],EA[3],EA[4],EA[5],EA[6],EA[7],EA[8],EA[9],EA[10],EA[11])
    PIN12(EA[12],EA[13],EA[14],EA[15],EA[16],EA[17],EA[18],EA[19],EA[20],EA[21],EA[22],EA[23])
    PIN12(EA[24],EA[25],EA[26],EA[27],EA[28],EA[29],EA[30],EA[31],EA[32],EA[33],EA[34],EA[35])
    PIN12(EA[36],EA[37],EA[38],EA[39],EA[40],EA[41],EA[42],EA[43],EA[44],EA[45],EA[46],EA[47])
    PIN12(EA[48],EA[49],EA[50],EA[51],EA[52],EA[53],EA[54],EA[55],EA[56],EA[57],EA[58],EA[59])
    PIN12(EA[60],EA[61],EA[62],EA[63],EA[64],EA[65],EA[66],EA[67],EA[68],EA[69],EA[70],EA[71])
    PIN12(EA[72],EA[73],EA[74],EA[75],EA[76],EA[77],EA[78],EA[79],EA[80],EA[81],EA[82],EA[83])
    PIN12(EA[84],EA[85],EA[86],EA[87],EA[88],EA[89],EA[90],EA[91],EA[92],EA[93],EA[94],EA[95])
    PIN12(EB[0],EB[1],EB[2],EB[3],EB[4],EB[5],EB[6],EB[7],EB[8],EB[9],EB[10],EB[11])
    PIN12(EB[12],EB[13],EB[14],EB[15],EB[16],EB[17],EB[18],EB[19],EB[20],EB[21],EB[22],EB[23])
    PIN12(EB[24],EB[25],EB[26],EB[27],EB[28],EB[29],EB[30],EB[31],EB[32],EB[33],EB[34],EB[35])
    PIN12(EB[36],EB[37],EB[38],EB[39],EB[40],EB[41],EB[42],EB[43],EB[44],EB[45],EB[46],EB[47])
#undef PIN12

    // p_0 = delta(start_tag=94). Rows 0..63 by lane l; rows 64..95 by l<32.
    // start_tag 94 = 64+30 lives in the second half (r7's NaN: it was zeroed).
    p_lds[0][l] = 0.0f;
    if (l < 32) p_lds[0][64 + l] = (l == 30) ? 1.0f : 0.0f;

    const float* hA = h + (size_t)b * Tt * NT + l;    // row l emissions
    const float* hB = h + (size_t)b * Tt * NT + r2;   // row r2 emissions
    float hpA[PF], hpB[PF];
    #pragma unroll
    for (int k = 0; k < PF; ++k) {
        hpA[k] = hA[(size_t)k * NT];
        hpB[k] = hB[(size_t)k * NT];
    }

    const float Kc = __expf(-4.0f);
    float M = 0.0f, pkA = 0.0f, pkB = 0.0f;
    int cur = 0;

    for (int tb = 0; tb < Tt; tb += PF) {
        #pragma unroll
        for (int k = 0; k < PF; ++k) {
            const int t = tb + k;
            const float* pc = p_lds[cur];
            const float4* pa4 = reinterpret_cast<const float4*>(pc);
            const float4* pb4 = reinterpret_cast<const float4*>(pc + par * 48);

            // peel m=0 to recover p[0] for the normalizer probe
            const float4 q0 = pa4[0];
            const float p0 = q0.x;
            float a0 = EA[0]*q0.x, a1 = EA[1]*q0.y, a2 = EA[2]*q0.z, a3 = EA[3]*q0.w;
            #pragma unroll
            for (int m = 1; m < 24; ++m) {
                const float4 p4 = pa4[m];
                a0 = fmaf(EA[4*m+0], p4.x, a0);
                a1 = fmaf(EA[4*m+1], p4.y, a1);
                a2 = fmaf(EA[4*m+2], p4.z, a2);
                a3 = fmaf(EA[4*m+3], p4.w, a3);
            }
            float b0 = 0.f, b1 = 0.f, b2 = 0.f, b3 = 0.f;
            #pragma unroll
            for (int m = 0; m < 12; ++m) {
                const float4 p4 = pb4[m];
                b0 = fmaf(EB[4*m+0], p4.x, b0);
                b1 = fmaf(EB[4*m+1], p4.y, b1);
                b2 = fmaf(EB[4*m+2], p4.z, b2);
                b3 = fmaf(EB[4*m+3], p4.w, b3);
            }
            const float vA  = (a0 + a1) + (a2 + a3);
            const float vBh = (b0 + b1) + (b2 + b3);
            const float vB  = vBh + __shfl_xor(vBh, 1, 64);  // pair-combine

            const float u   = (t == 0) ? 1.0f : Kc * __builtin_amdgcn_rcpf(p0);
            const float ehA = __expf(hpA[k]);
            const float ehB = __expf(hpB[k]);
            // reissue prefetch for t+PF (clamped); no barriers => stays in flight
            int tn = t + PF; if (tn > Tt - 1) tn = Tt - 1;
            hpA[k] = hA[(size_t)tn * NT];
            hpB[k] = hB[(size_t)tn * NT];

            const bool msk = (t < L);
            const float wA = vA * ehA * u;
            const float wB = vB * ehB * u;
            pkA = msk ? wA : pkA;
            pkB = msk ? wB : pkB;
            M  -= msk ? __logf(u) : 0.0f;

            const int nxt = cur ^ 1;
            p_lds[nxt][l] = pkA;
            if (par == 0) p_lds[nxt][r2] = pkB;   // rows 64..95, written once
            cur = nxt;
        }
    }

    // out[b] = M + log( sum_i p_L[i] * exp(trans[end_tag, i]) )
    float term = pkA * __expf(trans[(NT - 1) * NT + l]);
    if (par == 0) term += pkB * __expf(trans[(NT - 1) * NT + r2]);
    #pragma unroll
    for (int s = 1; s < 64; s <<= 1) term += __shfl_xor(term, s, 64);
    if (l == 0) out[b] = M + __logf(term);
}

extern "C" void kernel_launch(void* const* d_in, const int* in_sizes, int n_in,
                              void* d_out, int out_size, void* d_ws, size_t ws_size,
                              hipStream_t stream) {
    const float* h       = (const float*)d_in[0];
    const int*   lengths = (const int*)d_in[1];
    const float* trans   = (const float*)d_in[2];
    float*       out     = (float*)d_out;
    (void)in_sizes; (void)n_in; (void)out_size; (void)d_ws; (void)ws_size;

    crf_fwd_kernel<<<Bb, 64, 0, stream>>>(h, lengths, trans, out);
}

// Round 9
// 591.708 us; speedup vs baseline: 1.0351x; 1.0351x over previous
//
#include <hip/hip_runtime.h>

#define Bb 256
#define Tt 1024
#define NT 96
#define PF 4    // h prefetch batch per chain; double-buffered => 4-8 step slack

// CRF forward (log partition) — TWO chains per block, 192 threads (3 waves).
// Thread (i = tid>>1 in [0,96), q = tid&1) owns E[i][q*48..q*48+47] =
// exp(trans) in 48 pinned VGPRs (shared by both chains — same trans).
// Per interval (one step t for BOTH chains):
//   v[i]  = sum_j E[i,j]*p[j]  for chain0 and chain1 (independent => their
//   LDS latency / FMA chains interleave; chain1 fills chain0's stall shadow)
//   w = v*exp(h_t[i])*u,  u = e^{-c}/p_prev[0]  (tag-0 probe, u=1 at t=0)
//   p' = (t<L) ? w : p;  M -= (t<L)?log(u):0    (per chain)
//   ONE lgkmcnt(0)+s_barrier covers both chains' p writes.
// Rationale (r6/r8 evidence): barrier+LDS round-trip ~650cy is per-INTERVAL;
// doubling work per interval halves its per-chain-step cost. r8 showed
// single-wave pays 4x issue + spill (VGPR 132 < 144 needed) => stay 3-wave.
__global__ __attribute__((amdgpu_flat_work_group_size(192, 192),
                          amdgpu_waves_per_eu(1, 1)))
void crf_fwd_kernel(
    const float* __restrict__ h,       // [B][T][NT]
    const int*   __restrict__ lengths, // [B]
    const float* __restrict__ trans,   // [NT][NT] trans[to, from]
    float* __restrict__ out)           // [B]
{
    const int blk = blockIdx.x;
    const int b0  = blk * 2, b1 = blk * 2 + 1;
    const int tid = threadIdx.x;
    const int i   = tid >> 1;          // 0..95 — every thread active
    const int q   = tid & 1;
    const int wave = tid >> 6;         // 0..2
    const int L0  = lengths[b0];
    const int L1  = lengths[b1];

    __shared__ float pl0[2][128];
    __shared__ float pl1[2][128];
    __shared__ float fin0[3], fin1[3];

    // E = exp(trans) row segment as 48 scalars, pinned (r6-validated).
    float E[48];
    {
        const float4* tr4 = reinterpret_cast<const float4*>(trans + i * NT + q * 48);
        #pragma unroll
        for (int m = 0; m < 12; ++m) {
            const float4 t4 = tr4[m];
            E[4*m+0] = __expf(t4.x);
            E[4*m+1] = __expf(t4.y);
            E[4*m+2] = __expf(t4.z);
            E[4*m+3] = __expf(t4.w);
        }
    }
    asm volatile("" : "+v"(E[0]),  "+v"(E[1]),  "+v"(E[2]),  "+v"(E[3]),
                      "+v"(E[4]),  "+v"(E[5]),  "+v"(E[6]),  "+v"(E[7]),
                      "+v"(E[8]),  "+v"(E[9]),  "+v"(E[10]), "+v"(E[11]));
    asm volatile("" : "+v"(E[12]), "+v"(E[13]), "+v"(E[14]), "+v"(E[15]),
                      "+v"(E[16]), "+v"(E[17]), "+v"(E[18]), "+v"(E[19]),
                      "+v"(E[20]), "+v"(E[21]), "+v"(E[22]), "+v"(E[23]));
    asm volatile("" : "+v"(E[24]), "+v"(E[25]), "+v"(E[26]), "+v"(E[27]),
                      "+v"(E[28]), "+v"(E[29]), "+v"(E[30]), "+v"(E[31]),
                      "+v"(E[32]), "+v"(E[33]), "+v"(E[34]), "+v"(E[35]));
    asm volatile("" : "+v"(E[36]), "+v"(E[37]), "+v"(E[38]), "+v"(E[39]),
                      "+v"(E[40]), "+v"(E[41]), "+v"(E[42]), "+v"(E[43]),
                      "+v"(E[44]), "+v"(E[45]), "+v"(E[46]), "+v"(E[47]));

    // p_0 = delta(start_tag=94); exp(-10000)==0 in fp32 matches reference
    if (tid < 128) {
        const float v0 = (tid == NT - 2) ? 1.0f : 0.0f;
        pl0[0][tid] = v0;
        pl1[0][tid] = v0;
    }

    const float* h0 = h + (size_t)b0 * Tt * NT + i;
    const float* h1 = h + (size_t)b1 * Tt * NT + i;
    float hp0A[PF], hp0B[PF], hp1A[PF], hp1B[PF];
    #pragma unroll
    for (int k = 0; k < PF; ++k) {
        hp0A[k] = h0[(size_t)k * NT];
        hp1A[k] = h1[(size_t)k * NT];
        hp0B[k] = h0[(size_t)(PF + k) * NT];
        hp1B[k] = h1[(size_t)(PF + k) * NT];
    }

    const float Kc = __expf(-4.0f);
    float M0 = 0.0f, M1 = 0.0f, pk0 = 0.0f, pk1 = 0.0f;

    __syncthreads();   // one-time init sync

    int cur = 0;

#define STEP2(H0R, H1R, T_)                                                   \
    {                                                                         \
        const float p00 = pl0[cur][0];                                        \
        const float p10 = pl1[cur][0];                                        \
        const float4* pv0 = reinterpret_cast<const float4*>(pl0[cur] + q*48); \
        const float4* pv1 = reinterpret_cast<const float4*>(pl1[cur] + q*48); \
        float a0 = 0.f, a1 = 0.f, a2 = 0.f, a3 = 0.f;                         \
        float c0 = 0.f, c1 = 0.f, c2 = 0.f, c3 = 0.f;                         \
        _Pragma("unroll")                                                     \
        for (int m_ = 0; m_ < 12; ++m_) {                                     \
            const float4 x4 = pv0[m_];                                        \
            const float4 y4 = pv1[m_];                                        \
            a0 = fmaf(E[4*m_+0], x4.x, a0);                                   \
            a1 = fmaf(E[4*m_+1], x4.y, a1);                                   \
            a2 = fmaf(E[4*m_+2], x4.z, a2);                                   \
            a3 = fmaf(E[4*m_+3], x4.w, a3);                                   \
            c0 = fmaf(E[4*m_+0], y4.x, c0);                                   \
            c1 = fmaf(E[4*m_+1], y4.y, c1);                                   \
            c2 = fmaf(E[4*m_+2], y4.z, c2);                                   \
            c3 = fmaf(E[4*m_+3], y4.w, c3);                                   \
        }                                                                     \
        float v0 = (a0 + a1) + (a2 + a3);                                     \
        float v1 = (c0 + c1) + (c2 + c3);                                     \
        v0 += __shfl_xor(v0, 1, 64);                                          \
        v1 += __shfl_xor(v1, 1, 64);                                          \
        const float u0 = ((T_) == 0) ? 1.0f : Kc * __builtin_amdgcn_rcpf(p00);\
        const float u1 = ((T_) == 0) ? 1.0f : Kc * __builtin_amdgcn_rcpf(p10);\
        const float w0 = v0 * __expf(H0R) * u0;                               \
        const float w1 = v1 * __expf(H1R) * u1;                               \
        const bool mk0 = ((T_) < L0);                                         \
        const bool mk1 = ((T_) < L1);                                         \
        pk0 = mk0 ? w0 : pk0;                                                 \
        pk1 = mk1 ? w1 : pk1;                                                 \
        M0 -= mk0 ? __logf(u0) : 0.0f;                                        \
        M1 -= mk1 ? __logf(u1) : 0.0f;                                        \
        if (q == 0) { pl0[cur ^ 1][i] = pk0; pl1[cur ^ 1][i] = pk1; }         \
        asm volatile("s_waitcnt lgkmcnt(0)" ::: "memory");                    \
        __builtin_amdgcn_s_barrier();                                         \
        asm volatile("" ::: "memory");                                        \
        cur ^= 1;                                                             \
    }

    for (int tb = 0; tb < Tt; tb += 2 * PF) {
        #pragma unroll
        for (int k = 0; k < PF; ++k) STEP2(hp0A[k], hp1A[k], tb + k);

        #pragma unroll
        for (int m = 0; m < PF; ++m) {          // reload A <- t = tb+8..tb+11
            int tn = tb + 2 * PF + m; if (tn > Tt - 1) tn = Tt - 1;
            hp0A[m] = h0[(size_t)tn * NT];
            hp1A[m] = h1[(size_t)tn * NT];
        }

        #pragma unroll
        for (int k = 0; k < PF; ++k) STEP2(hp0B[k], hp1B[k], tb + PF + k);

        #pragma unroll
        for (int m = 0; m < PF; ++m) {          // reload B <- t = tb+12..tb+15
            int tn = tb + 3 * PF + m; if (tn > Tt - 1) tn = Tt - 1;
            hp0B[m] = h0[(size_t)tn * NT];
            hp1B[m] = h1[(size_t)tn * NT];
        }
    }
#undef STEP2

    // out[b] = M + log( sum_i p_L[i] * exp(trans[end_tag, i]) )
    const float eT = __expf(trans[(NT - 1) * NT + i]);
    float t0 = (q == 0) ? pk0 * eT : 0.0f;
    float t1 = (q == 0) ? pk1 * eT : 0.0f;
    #pragma unroll
    for (int s = 1; s < 64; s <<= 1) {
        t0 += __shfl_xor(t0, s, 64);
        t1 += __shfl_xor(t1, s, 64);
    }
    if ((tid & 63) == 0) { fin0[wave] = t0; fin1[wave] = t1; }
    __syncthreads();
    if (tid == 0) {
        out[b0] = M0 + __logf(fin0[0] + fin0[1] + fin0[2]);
        out[b1] = M1 + __logf(fin1[0] + fin1[1] + fin1[2]);
    }
}

extern "C" void kernel_launch(void* const* d_in, const int* in_sizes, int n_in,
                              void* d_out, int out_size, void* d_ws, size_t ws_size,
                              hipStream_t stream) {
    const float* h       = (const float*)d_in[0];
    const int*   lengths = (const int*)d_in[1];
    const float* trans   = (const float*)d_in[2];
    float*       out     = (float*)d_out;
    (void)in_sizes; (void)n_in; (void)out_size; (void)d_ws; (void)ws_size;

    crf_fwd_kernel<<<Bb / 2, 192, 0, stream>>>(h, lengths, trans, out);
}

// Round 10
// 390.195 us; speedup vs baseline: 1.5697x; 1.5164x over previous
//
#include <hip/hip_runtime.h>

#define Bb 256
#define Tt 1024
#define NT 96
#define PF 4   // h prefetch depth per row-stream; lgkm-only barriers keep loads in flight

// CRF forward (log partition) — one block per batch element, 128 threads (2 waves).
// Replication-blocked all-to-all (r6/r8/r9 evidence: interval ~ 490cy + 40cy
// per LDS broadcast-read instr): thread (g = tid>>2, cg = tid&3) reads p-cols
// [24cg, 24cg+24) ONCE (6 ds_read_b128) and reuses them for THREE rows
// {g, 32+g, 64+g} (72 FMA). Total reads/step: 2304 (r6) -> 768. Quad combine
// via shfl_xor(1,2). E = 72 pinned VGPRs (fits under the ~132 alloc cap seen
// in r8 -> no spill).
//   v[r] = sum_j E[r,j] p[j];  w = v*exp(h_t[r])*u;  u = e^{-c}/p_prev[0]
//   p' = (t<L) ? w : p;  M -= (t<L) ? log(u) : 0
// Barrier = lgkmcnt(0)-only + s_barrier (no vmcnt drain; h stays in flight).
__global__ __attribute__((amdgpu_flat_work_group_size(128, 128),
                          amdgpu_waves_per_eu(1, 1)))
void crf_fwd_kernel(
    const float* __restrict__ h,       // [B][T][NT]
    const int*   __restrict__ lengths, // [B]
    const float* __restrict__ trans,   // [NT][NT] trans[to, from]
    float* __restrict__ out)           // [B]
{
    const int b    = blockIdx.x;
    const int tid  = threadIdx.x;      // 0..127
    const int g    = tid >> 2;         // 0..31 row group
    const int cg   = tid & 3;          // 0..3 column quarter
    const int r0   = g, r1 = 32 + g, r2 = 64 + g;
    const int L    = lengths[b];
    const int wave = tid >> 6;

    __shared__ float p_lds[2][96];
    __shared__ float fin[2];

    // E rows (exp of trans), 3 rows x 24 cols = 72 scalars, pinned.
    float E0[24], E1[24], E2[24];
    {
        const float4* a = reinterpret_cast<const float4*>(trans + r0 * NT + cg * 24);
        const float4* c = reinterpret_cast<const float4*>(trans + r1 * NT + cg * 24);
        const float4* d = reinterpret_cast<const float4*>(trans + r2 * NT + cg * 24);
        #pragma unroll
        for (int m = 0; m < 6; ++m) {
            float4 t4 = a[m];
            E0[4*m+0]=__expf(t4.x); E0[4*m+1]=__expf(t4.y);
            E0[4*m+2]=__expf(t4.z); E0[4*m+3]=__expf(t4.w);
        }
        #pragma unroll
        for (int m = 0; m < 6; ++m) {
            float4 t4 = c[m];
            E1[4*m+0]=__expf(t4.x); E1[4*m+1]=__expf(t4.y);
            E1[4*m+2]=__expf(t4.z); E1[4*m+3]=__expf(t4.w);
        }
        #pragma unroll
        for (int m = 0; m < 6; ++m) {
            float4 t4 = d[m];
            E2[4*m+0]=__expf(t4.x); E2[4*m+1]=__expf(t4.y);
            E2[4*m+2]=__expf(t4.z); E2[4*m+3]=__expf(t4.w);
        }
    }
#define PIN12(A) \
    asm volatile("" : "+v"(A[0]), "+v"(A[1]), "+v"(A[2]),  "+v"(A[3]), \
                      "+v"(A[4]), "+v"(A[5]), "+v"(A[6]),  "+v"(A[7]), \
                      "+v"(A[8]), "+v"(A[9]), "+v"(A[10]), "+v"(A[11]));
#define PIN12H(A) \
    asm volatile("" : "+v"(A[12]), "+v"(A[13]), "+v"(A[14]), "+v"(A[15]), \
                      "+v"(A[16]), "+v"(A[17]), "+v"(A[18]), "+v"(A[19]), \
                      "+v"(A[20]), "+v"(A[21]), "+v"(A[22]), "+v"(A[23]));
    PIN12(E0) PIN12H(E0) PIN12(E1) PIN12H(E1) PIN12(E2) PIN12H(E2)
#undef PIN12
#undef PIN12H

    // p_0 = delta(start_tag=94); exp(-10000)==0 in fp32 matches reference
    if (tid < 96) p_lds[0][tid] = (tid == 94) ? 1.0f : 0.0f;

    const float* hbase = h + (size_t)b * Tt * NT;
    const float* hA = hbase + r0;
    const float* hB = hbase + r1;
    const float* hC = hbase + r2;
    float hp0[PF], hp1[PF], hp2[PF];
    #pragma unroll
    for (int k = 0; k < PF; ++k) {
        hp0[k] = hA[(size_t)k * NT];
        hp1[k] = hB[(size_t)k * NT];
        hp2[k] = hC[(size_t)k * NT];
    }

    const float Kc = __expf(-4.0f);
    float M = 0.0f, pk0 = 0.0f, pk1 = 0.0f, pk2 = 0.0f;

    __syncthreads();   // one-time init sync

    int cur = 0;
    for (int tb = 0; tb < Tt; tb += PF) {
        #pragma unroll
        for (int k = 0; k < PF; ++k) {
            const int t = tb + k;
            const float p0 = p_lds[cur][0];
            const float4* pv = reinterpret_cast<const float4*>(p_lds[cur] + cg * 24);

            // 3 row-dots over this thread's 24 columns (2 accums/row)
            float a0=0.f, a1=0.f, b0=0.f, b1=0.f, c0=0.f, c1=0.f;
            #pragma unroll
            for (int m = 0; m < 6; ++m) {
                const float4 p4 = pv[m];
                a0 = fmaf(E0[4*m+0], p4.x, a0);
                a1 = fmaf(E0[4*m+1], p4.y, a1);
                a0 = fmaf(E0[4*m+2], p4.z, a0);
                a1 = fmaf(E0[4*m+3], p4.w, a1);
                b0 = fmaf(E1[4*m+0], p4.x, b0);
                b1 = fmaf(E1[4*m+1], p4.y, b1);
                b0 = fmaf(E1[4*m+2], p4.z, b0);
                b1 = fmaf(E1[4*m+3], p4.w, b1);
                c0 = fmaf(E2[4*m+0], p4.x, c0);
                c1 = fmaf(E2[4*m+1], p4.y, c1);
                c0 = fmaf(E2[4*m+2], p4.z, c0);
                c1 = fmaf(E2[4*m+3], p4.w, c1);
            }
            float v0 = a0 + a1, v1 = b0 + b1, v2 = c0 + c1;
            // quad combine: full 24*4=96-col sums on all 4 lanes of the quad
            v0 += __shfl_xor(v0, 1, 64); v0 += __shfl_xor(v0, 2, 64);
            v1 += __shfl_xor(v1, 1, 64); v1 += __shfl_xor(v1, 2, 64);
            v2 += __shfl_xor(v2, 1, 64); v2 += __shfl_xor(v2, 2, 64);

            const float u   = (t == 0) ? 1.0f : Kc * __builtin_amdgcn_rcpf(p0);
            const float eh0 = __expf(hp0[k]);
            const float eh1 = __expf(hp1[k]);
            const float eh2 = __expf(hp2[k]);
            // reissue prefetch (clamped); loads stay in flight across barriers
            int tn = t + PF; if (tn > Tt - 1) tn = Tt - 1;
            hp0[k] = hA[(size_t)tn * NT];
            hp1[k] = hB[(size_t)tn * NT];
            hp2[k] = hC[(size_t)tn * NT];

            const bool msk = (t < L);
            pk0 = msk ? v0 * eh0 * u : pk0;
            pk1 = msk ? v1 * eh1 * u : pk1;
            pk2 = msk ? v2 * eh2 * u : pk2;
            M  -= msk ? __logf(u) : 0.0f;

            const int nxt = cur ^ 1;
            if (cg == 0) {
                p_lds[nxt][r0] = pk0;
                p_lds[nxt][r1] = pk1;
                p_lds[nxt][r2] = pk2;
            }
            asm volatile("s_waitcnt lgkmcnt(0)" ::: "memory");
            __builtin_amdgcn_s_barrier();
            asm volatile("" ::: "memory");
            cur = nxt;
        }
    }

    // out[b] = M + log( sum_i p_L[i] * exp(trans[end_tag, i]) )
    float term = 0.0f;
    if (cg == 0) {
        term = pk0 * __expf(trans[95 * NT + r0])
             + pk1 * __expf(trans[95 * NT + r1])
             + pk2 * __expf(trans[95 * NT + r2]);
    }
    #pragma unroll
    for (int s = 1; s < 64; s <<= 1) term += __shfl_xor(term, s, 64);
    if ((tid & 63) == 0) fin[wave] = term;
    __syncthreads();
    if (tid == 0) out[b] = M + __logf(fin[0] + fin[1]);
}

extern "C" void kernel_launch(void* const* d_in, const int* in_sizes, int n_in,
                              void* d_out, int out_size, void* d_ws, size_t ws_size,
                              hipStream_t stream) {
    const float* h       = (const float*)d_in[0];
    const int*   lengths = (const int*)d_in[1];
    const float* trans   = (const float*)d_in[2];
    float*       out     = (float*)d_out;
    (void)in_sizes; (void)n_in; (void)out_size; (void)d_ws; (void)ws_size;

    crf_fwd_kernel<<<Bb, 128, 0, stream>>>(h, lengths, trans, out);
}